// Round 1
// baseline (393.524 us; speedup 1.0000x reference)
//
#include <hip/hip_runtime.h>
#include <stdint.h>

// ImpulseNoise (salt & pepper), bit-exact re-implementation of JAX threefry2x32
// under the jax_threefry_partitionable=True (modern default) code path.
//
// key(42) = (0, 42)
// split:   k_flip = TF(key, (0,0)),  k_salt = TF(key, (0,1))   [fold-like split]
// bits[i] = TF(k, (0, i)).x0 ^ TF(k, (0, i)).x1                [partitionable bits]
// u       = bitcast_f32((bits >> 9) | 0x3F800000) - 1.0f
// out     = (u_flip <= 0.09f) ? ((u_salt <= 0.5f) ? 1.0f : 0.0f) : img

__host__ __device__ constexpr uint32_t rotl32(uint32_t x, int r) {
    return (x << r) | (x >> (32 - r));
}

struct TF2 { uint32_t a, b; };

__host__ __device__ constexpr TF2 threefry2x32(uint32_t k0, uint32_t k1,
                                               uint32_t x0, uint32_t x1) {
    const uint32_t ks0 = k0;
    const uint32_t ks1 = k1;
    const uint32_t ks2 = k0 ^ k1 ^ 0x1BD11BDAu;
    x0 += ks0; x1 += ks1;
    // rounds 1-4 (rot set A: 13,15,26,6)
    x0 += x1; x1 = rotl32(x1, 13); x1 ^= x0;
    x0 += x1; x1 = rotl32(x1, 15); x1 ^= x0;
    x0 += x1; x1 = rotl32(x1, 26); x1 ^= x0;
    x0 += x1; x1 = rotl32(x1,  6); x1 ^= x0;
    x0 += ks1; x1 += ks2 + 1u;
    // rounds 5-8 (rot set B: 17,29,16,24)
    x0 += x1; x1 = rotl32(x1, 17); x1 ^= x0;
    x0 += x1; x1 = rotl32(x1, 29); x1 ^= x0;
    x0 += x1; x1 = rotl32(x1, 16); x1 ^= x0;
    x0 += x1; x1 = rotl32(x1, 24); x1 ^= x0;
    x0 += ks2; x1 += ks0 + 2u;
    // rounds 9-12 (A)
    x0 += x1; x1 = rotl32(x1, 13); x1 ^= x0;
    x0 += x1; x1 = rotl32(x1, 15); x1 ^= x0;
    x0 += x1; x1 = rotl32(x1, 26); x1 ^= x0;
    x0 += x1; x1 = rotl32(x1,  6); x1 ^= x0;
    x0 += ks0; x1 += ks1 + 3u;
    // rounds 13-16 (B)
    x0 += x1; x1 = rotl32(x1, 17); x1 ^= x0;
    x0 += x1; x1 = rotl32(x1, 29); x1 ^= x0;
    x0 += x1; x1 = rotl32(x1, 16); x1 ^= x0;
    x0 += x1; x1 = rotl32(x1, 24); x1 ^= x0;
    x0 += ks1; x1 += ks2 + 4u;
    // rounds 17-20 (A)
    x0 += x1; x1 = rotl32(x1, 13); x1 ^= x0;
    x0 += x1; x1 = rotl32(x1, 15); x1 ^= x0;
    x0 += x1; x1 = rotl32(x1, 26); x1 ^= x0;
    x0 += x1; x1 = rotl32(x1,  6); x1 ^= x0;
    x0 += ks2; x1 += ks0 + 5u;
    return {x0, x1};
}

// Host-constexpr key derivation: seed 42 -> key (0, 42); fold-like split.
constexpr uint32_t SEED_HI = 0u;
constexpr uint32_t SEED_LO = 42u;
constexpr TF2 KFLIP = threefry2x32(SEED_HI, SEED_LO, 0u, 0u);
constexpr TF2 KSALT = threefry2x32(SEED_HI, SEED_LO, 0u, 1u);

__global__ __launch_bounds__(256)
void ImpulseNoise_32040456028513_kernel(const float4* __restrict__ in,
                                        float4* __restrict__ out,
                                        unsigned n4) {
    unsigned tid = blockIdx.x * blockDim.x + threadIdx.x;
    if (tid >= n4) return;

    float4 v = in[tid];
    float r[4] = {v.x, v.y, v.z, v.w};
    const uint32_t base = tid << 2;

#pragma unroll
    for (int j = 0; j < 4; ++j) {
        const uint32_t i = base + (uint32_t)j;
        // Two independent cipher chains per element -> good ILP; masked-lane
        // skipping of the salt cipher would save nothing (>=1 of 64 lanes
        // flips with p=0.997), so compute unconditionally.
        TF2 bf = threefry2x32(KFLIP.a, KFLIP.b, 0u, i);
        TF2 bs = threefry2x32(KSALT.a, KSALT.b, 0u, i);
        uint32_t bits_f = bf.a ^ bf.b;
        uint32_t bits_s = bs.a ^ bs.b;
        float uf = __uint_as_float((bits_f >> 9) | 0x3F800000u) - 1.0f;
        float us = __uint_as_float((bits_s >> 9) | 0x3F800000u) - 1.0f;
        bool flip = (uf <= 0.09f);
        float sp = (us <= 0.5f) ? 1.0f : 0.0f;
        r[j] = flip ? sp : r[j];
    }

    out[tid] = make_float4(r[0], r[1], r[2], r[3]);
}

extern "C" void kernel_launch(void* const* d_in, const int* in_sizes, int n_in,
                              void* d_out, int out_size, void* d_ws, size_t ws_size,
                              hipStream_t stream) {
    const float4* in = (const float4*)d_in[0];
    float4* out = (float4*)d_out;
    unsigned n = (unsigned)in_sizes[0];   // 64*3*512*512 = 50331648, divisible by 4
    unsigned n4 = n >> 2;
    unsigned blocks = (n4 + 255u) / 256u;
    ImpulseNoise_32040456028513_kernel<<<blocks, 256, 0, stream>>>(in, out, n4);
}